// Round 10
// baseline (1031.736 us; speedup 1.0000x reference)
//
#include <hip/hip_runtime.h>

typedef unsigned short ushort_t;
typedef float  f4v  __attribute__((ext_vector_type(4)));
typedef __bf16 bf4v __attribute__((ext_vector_type(4)));
typedef __bf16 bf8v __attribute__((ext_vector_type(8)));
typedef ushort_t us4 __attribute__((ext_vector_type(4)));

#define NDIM 512
#define NCOL 65536
#define NSTEPS 20
#define NBLK 64      // grid of the sinkhorn kernel; 64 blocks << 256 CUs -> co-resident
#define NBAR 41      // 1 (post-transpose) + 2*NSTEPS single-use barrier slots

__device__ __forceinline__ ushort_t f2bf(float f) {
  unsigned u = __float_as_uint(f);
  u = (u + 0x7fffu + ((u >> 16) & 1u)) >> 16;
  return (ushort_t)u;
}
__device__ __forceinline__ float bf2f(ushort_t h) {
  return __uint_as_float(((unsigned)h) << 16);
}

// ---------------- manual device-scope grid barrier (regular launch, graph-safe) ----
// Single-use counter per barrier slot; zeroed by init_k every call. Arrival:
// release fence + device-scope atomicAdd (m20: device-scope by default). Spin:
// atomicAdd(ptr,0) RMW-read (coherent across XCDs). Exit: threadfence to drop
// stale L1/L2 lines before re-reading r/c written by other XCDs.
__device__ __forceinline__ void gbar(int* __restrict__ bar, int idx) {
  __syncthreads();
  __threadfence();  // each thread publishes its own prior stores (device scope)
  if (threadIdx.x == 0) {
    atomicAdd(&bar[idx], 1);
    while (atomicAdd(&bar[idx], 0) < NBLK) __builtin_amdgcn_s_sleep(2);
  }
  __syncthreads();
  __threadfence();  // acquire: invalidate stale cached lines
}

// ---------------- init: zero barrier slots + r,c (ws is poisoned 0xAA every call) ----
__global__ void init_k(float* __restrict__ r, float* __restrict__ c,
                       int* __restrict__ bar) {
  int t = threadIdx.x;
  r[t] = 0.f;
  c[t] = 0.f;
  if (t < 64) bar[t] = 0;
}

// one row's LSE: dst[row] = LSE_j(M[row][j] - sub[j]); whole wave participates.
__device__ __forceinline__ void lse_row(const float* __restrict__ M,
                                        const float* __restrict__ sub,
                                        float* __restrict__ dst, int row, int lane) {
  const f4v* mr = (const f4v*)(M + (size_t)row * NDIM);
  const f4v* sp = (const f4v*)sub;
  f4v a = mr[lane];
  f4v b = mr[lane + 64];
  f4v sa = sp[lane];
  f4v sb = sp[lane + 64];
  float v[8];
  v[0] = a[0] - sa[0]; v[1] = a[1] - sa[1]; v[2] = a[2] - sa[2]; v[3] = a[3] - sa[3];
  v[4] = b[0] - sb[0]; v[5] = b[1] - sb[1]; v[6] = b[2] - sb[2]; v[7] = b[3] - sb[3];
  float m = v[0];
#pragma unroll
  for (int i = 1; i < 8; ++i) m = fmaxf(m, v[i]);
#pragma unroll
  for (int off = 32; off > 0; off >>= 1) m = fmaxf(m, __shfl_xor(m, off));
  float s = 0.f;
#pragma unroll
  for (int i = 0; i < 8; ++i) s += expf(v[i] - m);
#pragma unroll
  for (int off = 32; off > 0; off >>= 1) s += __shfl_xor(s, off);
  if (lane == 0) dst[row] = m + logf(s);
}

// ---------------- fused sinkhorn with MANUAL grid barriers (no coop launch) -------
// 64 blocks x 512 threads; 1 wave per matrix row. Replaces both the 42-deep launch
// chain (~264us, round 2) and the cooperative-kernel version (round 7: graph replay
// corrupted the runtime's hidden grid.sync state -> post-timing divergence).
__global__ __launch_bounds__(512, 1) void sinkhorn_manual(
    const float* __restrict__ W, float* __restrict__ WT, float* __restrict__ r,
    float* __restrict__ c, ushort_t* __restrict__ Ahi, ushort_t* __restrict__ Alo,
    int* __restrict__ bar) {
  const int tid = threadIdx.x;
  const int bid = blockIdx.x;

  // ---- phase 0: WT = W^T (4 tiles of 32x32 per block) ----
  {
    __shared__ float tile[4][32][33];
    int sub = tid >> 7;              // 0..3
    int t2 = tid & 127;
    int tx = t2 & 31, tg = t2 >> 5;  // 32 x 4
    int tindex = bid * 4 + sub;      // 0..255
    int by = (tindex >> 4) * 32;
    int bx = (tindex & 15) * 32;
#pragma unroll
    for (int i = 0; i < 8; ++i) {
      int row = tg * 8 + i;
      tile[sub][row][tx] = W[(size_t)(by + row) * NDIM + bx + tx];
    }
    __syncthreads();
#pragma unroll
    for (int i = 0; i < 8; ++i) {
      int row = tg * 8 + i;
      WT[(size_t)(bx + row) * NDIM + by + tx] = tile[sub][tx][row];
    }
  }
  gbar(bar, 0);

  // ---- phase 1: 20 Gauss-Seidel iterations, one barrier per half-step ----
  int lane = tid & 63;
  int wave = tid >> 6;
  int row = bid * 8 + wave;  // 64 blocks * 8 waves = 512 rows
  for (int it = 0; it < NSTEPS; ++it) {
    lse_row(W, c, r, row, lane);   // r_i = LSE_j(W - c)
    gbar(bar, 1 + 2 * it);
    lse_row(WT, r, c, row, lane);  // c_j = LSE_i(W - r)
    gbar(bar, 2 + 2 * it);
  }

  // ---- phase 2: dsm = exp(W - r - c), split bf16 hi/lo ----
  int gidx = bid * 512 + tid;  // 0..32767, 2 quads each
#pragma unroll
  for (int q = 0; q < 2; ++q) {
    int idx = gidx * 2 + q;  // 0..65535
    int m = idx >> 7;
    int kq = idx & 127;
    f4v w = ((const f4v*)(W + (size_t)m * NDIM))[kq];
    f4v cc = ((const f4v*)c)[kq];
    float rm = r[m];
    us4 vh, vl;
#pragma unroll
    for (int i = 0; i < 4; ++i) {
      float v = expf(w[i] - rm - cc[i]);
      ushort_t h = f2bf(v);
      float res = v - bf2f(h);
      vh[i] = h;
      vl[i] = f2bf(res);
    }
    size_t base = (size_t)m * NDIM + kq * 4;
    *(us4*)(Ahi + base) = vh;
    *(us4*)(Alo + base) = vl;
  }
}

// ---------------- GEMM: out[512][65536] = dsm @ x, 3-term bf16 split ----------------
// Validated correct in round 7 (first-call absmax 2e-3). BM=128 BN=128 BK=32,
// 4 waves 2x2, wave tile 64x64 (4x4 frags of 16x16x32). A global->reg direct
// (L2-resident). B reg-staged to LDS, [n][k] k-contig, XOR swizzle ((n>>2)&7)<<2
// on k (write AND read). T14: next K-tile's X loads issued before frag-reads+MFMA.
__global__ __launch_bounds__(256, 3) void gemm_k(const float* __restrict__ X,
                                                 const ushort_t* __restrict__ Ahi,
                                                 const ushort_t* __restrict__ Alo,
                                                 float* __restrict__ out) {
  __shared__ ushort_t sBhi[128 * 32];
  __shared__ ushort_t sBlo[128 * 32];

  int bid = blockIdx.x;
  int swz = (bid & 7) * 256 + (bid >> 3);  // XCD-chunked, bijective (2048 % 8 == 0)
  int nt = swz >> 2;
  int mt = swz & 3;

  int tid = threadIdx.x;
  int lane = tid & 63;
  int w = tid >> 6;
  int wr = w >> 1, wc = w & 1;

  int n4 = tid & 31;
  int fs_w = (n4 & 7) << 2;
  int kbase = (tid >> 5) * 2;  // 0,2,..,14 ; +16 for second pair

  const ushort_t* Abase_hi =
      Ahi + (size_t)(mt * 128 + wr * 64 + (lane & 15)) * NDIM + (lane >> 4) * 8;
  const ushort_t* Abase_lo =
      Alo + (size_t)(mt * 128 + wr * 64 + (lane & 15)) * NDIM + (lane >> 4) * 8;

  f4v acc[4][4];
#pragma unroll
  for (int i = 0; i < 4; ++i)
#pragma unroll
    for (int j = 0; j < 4; ++j) acc[i][j] = (f4v)0.f;

  // prologue: X loads for kt=0
  f4v va[2], vb[2];
#pragma unroll
  for (int it = 0; it < 2; ++it) {
    int k = kbase + it * 16;
    va[it] = *((const f4v*)(X + (size_t)k * NCOL + nt * 128) + n4);
    vb[it] = *((const f4v*)(X + (size_t)(k + 1) * NCOL + nt * 128) + n4);
  }

  for (int kt = 0; kt < 16; ++kt) {
    // ---- split + LDS write for tile kt (from prefetched regs) ----
#pragma unroll
    for (int it = 0; it < 2; ++it) {
      int k = kbase + it * 16;
      f4v xa = va[it], xb = vb[it];
#pragma unroll
      for (int cx = 0; cx < 4; ++cx) {
        int nn = n4 * 4 + cx;
        float x0 = xa[cx], x1 = xb[cx];
        ushort_t h0 = f2bf(x0), h1 = f2bf(x1);
        float r0 = x0 - bf2f(h0), r1 = x1 - bf2f(h1);
        ushort_t l0 = f2bf(r0), l1 = f2bf(r1);
        int idx2 = nn * 32 + (k ^ fs_w);  // even
        *(unsigned*)(&sBhi[idx2]) = (unsigned)h0 | ((unsigned)h1 << 16);
        *(unsigned*)(&sBlo[idx2]) = (unsigned)l0 | ((unsigned)l1 << 16);
      }
    }
    __syncthreads();

    // ---- issue next tile's X loads (hide under frag-loads + MFMA) ----
    if (kt < 15) {
#pragma unroll
      for (int it = 0; it < 2; ++it) {
        int k = kbase + it * 16;
        const float* base = X + (size_t)((kt + 1) * 32 + k) * NCOL + nt * 128;
        va[it] = *((const f4v*)base + n4);
        vb[it] = *((const f4v*)(base + NCOL) + n4);
      }
    }

    // ---- A frags: global direct (L2) ----
    bf8v ah[4], al[4];
#pragma unroll
    for (int i = 0; i < 4; ++i) {
      ah[i] = *(const bf8v*)(Abase_hi + (size_t)i * 16 * NDIM + kt * 32);
      al[i] = *(const bf8v*)(Abase_lo + (size_t)i * 16 * NDIM + kt * 32);
    }
    // ---- B frags from LDS ----
    bf8v bh[4], bl[4];
#pragma unroll
    for (int j = 0; j < 4; ++j) {
      int nn = wc * 64 + j * 16 + (lane & 15);
      int fs = ((nn >> 2) & 7) << 2;
      int kc = (lane >> 4) * 8;
      int ia = nn * 32 + (kc ^ fs);
      int ib = nn * 32 + ((kc + 4) ^ fs);
      bf4v h0 = *(const bf4v*)(&sBhi[ia]);
      bf4v h1 = *(const bf4v*)(&sBhi[ib]);
      bf4v q0 = *(const bf4v*)(&sBlo[ia]);
      bf4v q1 = *(const bf4v*)(&sBlo[ib]);
      bf8v bhv, blv;
#pragma unroll
      for (int e = 0; e < 4; ++e) {
        bhv[e] = h0[e];
        bhv[e + 4] = h1[e];
        blv[e] = q0[e];
        blv[e + 4] = q1[e];
      }
      bh[j] = bhv;
      bl[j] = blv;
    }

    // ---- 48 MFMA (hi*hi + hi*lo + lo*hi) ----
#pragma unroll
    for (int i = 0; i < 4; ++i)
#pragma unroll
      for (int j = 0; j < 4; ++j) {
        acc[i][j] = __builtin_amdgcn_mfma_f32_16x16x32_bf16(ah[i], bh[j], acc[i][j], 0, 0, 0);
        acc[i][j] = __builtin_amdgcn_mfma_f32_16x16x32_bf16(ah[i], bl[j], acc[i][j], 0, 0, 0);
        acc[i][j] = __builtin_amdgcn_mfma_f32_16x16x32_bf16(al[i], bh[j], acc[i][j], 0, 0, 0);
      }
    __syncthreads();
  }

  // ---- epilogue: C/D layout col=lane&15, row=(lane>>4)*4+reg ----
  float* outp = out + (size_t)(mt * 128 + wr * 64 + (lane >> 4) * 4) * NCOL + nt * 128 +
                wc * 64 + (lane & 15);
#pragma unroll
  for (int i = 0; i < 4; ++i)
#pragma unroll
    for (int j = 0; j < 4; ++j)
#pragma unroll
      for (int rr = 0; rr < 4; ++rr)
        outp[(size_t)(i * 16 + rr) * NCOL + j * 16] = acc[i][j][rr];
}

// ---------------- launch ----------------
extern "C" void kernel_launch(void* const* d_in, const int* in_sizes, int n_in,
                              void* d_out, int out_size, void* d_ws, size_t ws_size,
                              hipStream_t stream) {
  const float* X = (const float*)d_in[0];  // [512][65536]
  const float* W = (const float*)d_in[1];  // [512][512]
  float* out = (float*)d_out;              // [512][65536]

  float* r = (float*)d_ws;
  float* c = r + NDIM;
  float* WT = c + NDIM;  // 512*512 f32
  ushort_t* Ahi = (ushort_t*)(WT + NDIM * NDIM);
  ushort_t* Alo = Ahi + NDIM * NDIM;
  int* bar = (int*)(Alo + NDIM * NDIM);  // 64 ints
  // ws usage ~2.1 MB (round 2 passed with the same extent)

  init_k<<<1, 512, 0, stream>>>(r, c, bar);
  sinkhorn_manual<<<NBLK, 512, 0, stream>>>(W, WT, r, c, Ahi, Alo, bar);
  gemm_k<<<2048, 256, 0, stream>>>(X, Ahi, Alo, out);
}